// Round 13
// baseline (100.379 us; speedup 1.0000x reference)
//
#include <hip/hip_runtime.h>
#include <hip/hip_bf16.h>

#define H 256
#define Wd 256
#define H2 128

typedef unsigned short ushort_t;
typedef __attribute__((ext_vector_type(8))) short short8;
typedef __attribute__((ext_vector_type(4))) float f32x4;

// guarded mish (k3: conv2 outputs can be larger; keep the clamp)
__device__ __forceinline__ float mishf(float v){
  if (v > 15.f) return v;
  float e = __expf(v);
  float w = e*(e+2.f);
  return v * w * __builtin_amdgcn_rcpf(w + 2.f);
}
// slim mish (conv1 outputs bounded -> no overflow possible)
__device__ __forceinline__ float mish_s(float v){
  float e = __expf(v);
  float w = e*(e+2.f);
  return v * w * __builtin_amdgcn_rcpf(w + 2.f);
}

__device__ __forceinline__ ushort_t f2bf(float f){
  unsigned int u = __float_as_uint(f);
  u += 0x7fffu + ((u >> 16) & 1u);
  return (ushort_t)(u >> 16);
}
__device__ __forceinline__ unsigned packbf(float a, float b){
  return (unsigned)f2bf(a) | ((unsigned)f2bf(b) << 16);
}
__device__ __forceinline__ float lo16(unsigned u){
  return __uint_as_float(u << 16);
}
__device__ __forceinline__ float hi16(unsigned u){
  return __uint_as_float(u & 0xffff0000u);
}

// ---------------------------------------------------------------------------
// shuf layout: 8-byte pixel records  [plane = b*16 + c][i*256 + j][m0..3]
// (bf16 x4). k12c writes top rows (own plane) and bottom rows (rolled plane).
// ---------------------------------------------------------------------------

// K0: pre-pack W2 into bf16 MFMA A-fragment order.
__global__ void k0_pack(const float* __restrict__ W2, ushort_t* __restrict__ wpack)
{
  int idx = blockIdx.x*128 + threadIdx.x;   // 0..1151
  if (idx >= 1152) return;
  int lane  = idx & 63;
  int s     = (idx >> 6) % 9;
  int khalf = idx / 576;
  int n = lane & 15, g = lane >> 4;
  unsigned int w[4];
#pragma unroll
  for (int h = 0; h < 4; ++h){
    int ch0 = khalf*32 + g*8 + 2*h;
    unsigned lo = f2bf(W2[(n*64 + ch0  )*9 + s]);
    unsigned hi = f2bf(W2[(n*64 + ch0+1)*9 + s]);
    w[h] = lo | (hi << 16);
  }
  *(uint4*)(wpack + (size_t)idx*8) = make_uint4(w[0], w[1], w[2], w[3]);
}

// ---------------------------------------------------------------------------
// K12C (v2): column-sweep, register-only (NO LDS, NO barriers).
// Thread = 4 cols x 2 out rows (grid 2048 = 8 blocks/CU for occupancy).
// Rolling 3-row register windows for x and f. Bottom first (g in regs,
// rolled-plane store), then top sweep: 4 f-rows, emit when 3 live.
// Span uses per-px combined weights wc = g*wsp + bsp.
// ---------------------------------------------------------------------------
__global__ __launch_bounds__(256) void k12c(
    const float* __restrict__ x, const float* __restrict__ W1,
    const float* __restrict__ b1, const float* __restrict__ Wred,
    const float* __restrict__ bred, const float* __restrict__ Wspan,
    const float* __restrict__ bspan, ushort_t* __restrict__ shuf)
{
  int bid0 = blockIdx.x;                    // 2048
  int bid  = (bid0 & 7)*256 + (bid0 >> 3);  // XCD-contiguous (1 batch/XCD)
  int n    = bid >> 4;                      // plane 0..127
  int L    = (bid & 15)*256 + threadIdx.x;  // 0..4095 within plane
  int band = L >> 6;                        // 0..63
  int strip= L & 63;                        // 0..63
  int r0 = band*2;                          // out rows r0..r0+1 (top)
  int jc = strip*4;
  const float* xp = x + (size_t)n*65536;
  bool jl = (jc == 0), jh = (jc == 252);
  int bq = n >> 4, cq = n & 15;
  const float4 f4z = make_float4(0.f,0.f,0.f,0.f);

  float w1r[36], b1r[4], wsp[9], bsp[9], wredr[4];
  float bredr = bred[0];
#pragma unroll
  for (int k=0;k<36;k++) w1r[k] = W1[k];
#pragma unroll
  for (int m=0;m<4;m++){ b1r[m] = b1[m]; wredr[m] = Wred[m]; }
#pragma unroll
  for (int k=0;k<9;k++){ wsp[k] = Wspan[k]; bsp[k] = bspan[k]; }

  // 6-wide row load (cols jc-1..jc+4), pred: row < 256
#define LOADB(row_, dst_) { \
    int rw = (row_); \
    bool rok = (rw < 256); \
    const float* rp = xp + rw*256 + jc; \
    float4 m_ = rok ? *(const float4*)rp : f4z; \
    float l_ = (rok && !jl) ? rp[-1] : 0.f; \
    float r_ = (rok && !jh) ? rp[4]  : 0.f; \
    dst_[0]=l_; dst_[1]=m_.x; dst_[2]=m_.y; dst_[3]=m_.z; dst_[4]=m_.w; dst_[5]=r_; }

  // 8-wide row load (cols jc-2..jc+5), pred: row >= 0
#define LOADT(row_, dst_) { \
    int rw = (row_); \
    bool rok = (rw >= 0); \
    const float* rp = xp + rw*256 + jc; \
    float4 m_ = rok ? *(const float4*)rp : f4z; \
    float4 l_ = (rok && !jl) ? *(const float4*)(rp-4) : f4z; \
    float4 r_ = (rok && !jh) ? *(const float4*)(rp+4) : f4z; \
    dst_[0]=l_.z; dst_[1]=l_.w; dst_[2]=m_.x; dst_[3]=m_.y; \
    dst_[4]=m_.z; dst_[5]=m_.w; dst_[6]=r_.x; dst_[7]=r_.y; }

  // ======== Bottom phase: rows 128+r0, 129+r0 ========
  float gv[2][4];                           // [rr][px]
  {
    float xb[3][6];
    LOADB(127+r0, xb[0]);
    LOADB(128+r0, xb[1]);
    int cdst = (cq + 15) & 15;
    size_t bplane = ((size_t)(bq*16 + cdst))*65536;
#pragma unroll
    for (int rr=0; rr<2; ++rr){
      LOADB(129+r0+rr, xb[(rr+2)%3]);
      // x rows: br-1 -> xb[rr%3], br -> xb[(rr+1)%3], br+1 -> xb[(rr+2)%3]
      float fbv[4][4];                      // [m][px]
#pragma unroll
      for (int m=0;m<4;m++)
#pragma unroll
        for (int p=0;p<4;p++){
          float s = b1r[m];
#pragma unroll
          for (int ky=0;ky<3;ky++){
            const float* xr = xb[(rr+ky)%3];
#pragma unroll
            for (int kx=0;kx<3;kx++)
              s = fmaf(xr[p+kx], w1r[m*9+ky*3+kx], s);
          }
          fbv[m][p] = mish_s(s);
        }
      size_t base = bplane + (size_t)(128+r0+rr)*256 + jc;
      unsigned pw[8];
#pragma unroll
      for (int p=0;p<4;p++){
        pw[p*2]   = packbf(fbv[0][p], fbv[1][p]);
        pw[p*2+1] = packbf(fbv[2][p], fbv[3][p]);
      }
      *(uint4*)(shuf + base*4)     = make_uint4(pw[0],pw[1],pw[2],pw[3]);
      *(uint4*)(shuf + (base+2)*4) = make_uint4(pw[4],pw[5],pw[6],pw[7]);
#pragma unroll
      for (int p=0;p<4;p++){
        float s = bredr;
#pragma unroll
        for (int m=0;m<4;m++) s = fmaf(fbv[m][p], wredr[m], s);
        gv[rr][p] = fmaxf(s, 0.f);
      }
    }
  }

  // ======== Top phase: sweep f rows r0-1 .. r0+2, emit rows r0..r0+1 ========
  float xw[3][8];
  unsigned fw[3][6][2];                     // [rowslot][colslot][m01,m23]
  LOADT(r0-2, xw[0]);
  LOADT(r0-1, xw[1]);
  size_t tplane = (size_t)n*65536;

#pragma unroll
  for (int s=0; s<4; ++s){
    LOADT(r0+s, xw[(s+2)%3]);
    int fr = r0 - 1 + s;
    // x rows for f(fr): fr-1 -> xw[s%3], fr -> xw[(s+1)%3], fr+1 -> xw[(s+2)%3]
    if ((unsigned)fr < 128u){
#pragma unroll
      for (int cc=0; cc<6; ++cc){
        float s0 = b1r[0], s1 = b1r[1], s2 = b1r[2], s3 = b1r[3];
#pragma unroll
        for (int ky=0;ky<3;ky++){
          const float* xr = xw[(s+ky)%3];
#pragma unroll
          for (int kx=0;kx<3;kx++){
            float xv = xr[cc+kx];
            s0 = fmaf(xv, w1r[   ky*3+kx], s0);
            s1 = fmaf(xv, w1r[ 9+ky*3+kx], s1);
            s2 = fmaf(xv, w1r[18+ky*3+kx], s2);
            s3 = fmaf(xv, w1r[27+ky*3+kx], s3);
          }
        }
        fw[s%3][cc][0] = packbf(mish_s(s0), mish_s(s1));
        fw[s%3][cc][1] = packbf(mish_s(s2), mish_s(s3));
      }
      if (jl){ fw[s%3][0][0]=0u; fw[s%3][0][1]=0u; }
      if (jh){ fw[s%3][5][0]=0u; fw[s%3][5][1]=0u; }
    } else {
#pragma unroll
      for (int cc=0; cc<6; ++cc){ fw[s%3][cc][0]=0u; fw[s%3][cc][1]=0u; }
    }

    if (s >= 2){
      int orow = fr - 1;                    // r0 + (s-2)
      // f rows: orow-1 -> fw[(s-2)%3], orow -> fw[(s-1)%3], orow+1 -> fw[s%3]
      unsigned pw[8];
#pragma unroll
      for (int p=0;p<4;p++){
        float gvp = gv[s-2][p];
        float o0=0.f, o1=0.f, o2=0.f, o3=0.f;
#pragma unroll
        for (int ky=0;ky<3;ky++){
          const unsigned (*fr_)[2] = fw[(s-2+ky)%3];
#pragma unroll
          for (int kx=0;kx<3;kx++){
            float wc = fmaf(gvp, wsp[ky*3+kx], bsp[ky*3+kx]);
            unsigned u0 = fr_[p+kx][0], u1 = fr_[p+kx][1];
            o0 = fmaf(lo16(u0), wc, o0);
            o1 = fmaf(hi16(u0), wc, o1);
            o2 = fmaf(lo16(u1), wc, o2);
            o3 = fmaf(hi16(u1), wc, o3);
          }
        }
        pw[p*2]   = packbf(o0, o1);
        pw[p*2+1] = packbf(o2, o3);
      }
      size_t tbase = tplane + (size_t)orow*256 + jc;
      *(uint4*)(shuf + tbase*4)     = make_uint4(pw[0],pw[1],pw[2],pw[3]);
      *(uint4*)(shuf + (tbase+2)*4) = make_uint4(pw[4],pw[5],pw[6],pw[7]);
    }
  }
#undef LOADB
#undef LOADT
}

// ---------------------------------------------------------------------------
// K3: conv2 via MFMA implicit GEMM, direct-from-global B fragments.
// ---------------------------------------------------------------------------
__global__ __launch_bounds__(256) void k3_conv2(
    const ushort_t* __restrict__ shuf, const ushort_t* __restrict__ wpack,
    const float* __restrict__ b2, float* __restrict__ scratch)
{
  __shared__ f32x4 mg[2][8][64];   // 16 KiB
  __shared__ float pacc[16];

  int bid0 = blockIdx.x;                     // 2048
  int bid  = (bid0 & 7)*256 + (bid0 >> 3);   // XCD-contiguous chunks
  int b   = bid >> 8;
  int t   = bid & 255;
  int rb  = t >> 3;
  int cb  = t & 7;
  int tid = threadIdx.x;
  int lane = tid & 63;
  int n = lane & 15;
  int g = lane >> 4;
  int wid = tid >> 6;
  int colhalf = wid & 1;
  int khalf   = wid >> 1;

  if (tid < 16) pacc[tid] = 0.f;

  const short8* wp = (const short8*)wpack + (size_t)khalf*576 + lane;
  short8 afr[9];
#pragma unroll
  for (int s = 0; s < 9; ++s) afr[s] = wp[s*64];

  f32x4 acc[8];
#pragma unroll
  for (int r = 0; r < 8; ++r) acc[r] = f32x4{0.f,0.f,0.f,0.f};

  int r0 = rb*8 - 1;
  int c  = cb*32 - 1 + colhalf*16 + n;
  int p0 = khalf*8 + g*2;
  const ushort_t* sp = shuf + ((size_t)(b*16 + p0))*262144;

#pragma unroll
  for (int hr = 0; hr < 10; ++hr){
    int grow = r0 + hr;
    bool rok = (unsigned)grow < 256u;
    uint2 va[3], vbv[3];
#pragma unroll
    for (int kx = 0; kx < 3; ++kx){
      int gcol = c + kx;
      uint2 a = make_uint2(0u,0u), bv = make_uint2(0u,0u);
      if (rok && (unsigned)gcol < 256u){
        const ushort_t* pp = sp + (size_t)(grow*256 + gcol)*4;
        a  = *(const uint2*)pp;
        bv = *(const uint2*)(pp + 262144);
      }
      va[kx] = a; vbv[kx] = bv;
    }
#pragma unroll
    for (int kx = 0; kx < 3; ++kx){
      union { uint4 u; short8 s; } cv;
      cv.u = make_uint4(va[kx].x, va[kx].y, vbv[kx].x, vbv[kx].y);
#pragma unroll
      for (int ky = 0; ky < 3; ++ky){
        int orow = hr - ky;
        if (orow >= 0 && orow < 8){
          acc[orow] = __builtin_amdgcn_mfma_f32_16x16x32_bf16(
              afr[ky*3+kx], cv.s, acc[orow], 0, 0, 0);
        }
      }
    }
  }

  if (khalf == 1){
#pragma unroll
    for (int r = 0; r < 8; ++r) mg[colhalf][r][lane] = acc[r];
  }
  __syncthreads();

  if (khalf == 0){
    float b2v[4];
#pragma unroll
    for (int q = 0; q < 4; ++q) b2v[q] = b2[g*4 + q];
    float po[4] = {0.f, 0.f, 0.f, 0.f};
#pragma unroll
    for (int r = 0; r < 8; ++r){
      f32x4 o = acc[r] + mg[colhalf][r][lane];
#pragma unroll
      for (int q = 0; q < 4; ++q) po[q] += mishf(o[q] + b2v[q]);
    }
#pragma unroll
    for (int q = 0; q < 4; ++q){
#pragma unroll
      for (int mk = 1; mk < 16; mk <<= 1) po[q] += __shfl_xor(po[q], mk);
    }
    if (n == 0){
#pragma unroll
      for (int q = 0; q < 4; ++q) atomicAdd(&pacc[g*4 + q], po[q]);
    }
  }
  __syncthreads();
  if (tid < 16) scratch[bid*16 + tid] = pacc[tid];
}

// K4: reduce per-block partials -> pooled mean -> ECA gate. One block per b.
__global__ void k4_gate(const float* __restrict__ scratch,
                        const float* __restrict__ Weca,
                        float* __restrict__ gate)
{
  __shared__ float rr[16][16];
  __shared__ float pool[16];
  int b = blockIdx.x;
  int t = threadIdx.x;           // 256
  int oc = t & 15, ch = t >> 4;
  float s = 0.f;
  for (int u = 0; u < 16; ++u)
    s += scratch[(size_t)(b*256 + ch*16 + u)*16 + oc];
  rr[ch][oc] = s;
  __syncthreads();
  if (t < 16){
    float tot = 0.f;
#pragma unroll
    for (int k = 0; k < 16; ++k) tot += rr[k][t];
    pool[t] = tot * (1.0f/65536.0f);
  }
  __syncthreads();
  if (t < 16){
    float pm = (t > 0)  ? pool[t-1] : 0.f;
    float p0 = pool[t];
    float pp = (t < 15) ? pool[t+1] : 0.f;
    float z = Weca[0]*pm + Weca[1]*p0 + Weca[2]*pp;
    gate[b*16 + t] = 1.f/(1.f + __expf(-z));
  }
}

// K5: out = x * gate[b,c], nontemporal load+store
__global__ __launch_bounds__(256) void k5_scale(
    const f32x4* __restrict__ x4, const float* __restrict__ gate,
    f32x4* __restrict__ out4)
{
  int idx = blockIdx.x*256 + threadIdx.x;
  float g = gate[idx >> 14];
  f32x4 v = __builtin_nontemporal_load(&x4[idx]) * g;
  __builtin_nontemporal_store(v, &out4[idx]);
}

extern "C" void kernel_launch(void* const* d_in, const int* in_sizes, int n_in,
                              void* d_out, int out_size, void* d_ws, size_t ws_size,
                              hipStream_t stream)
{
  const float* x     = (const float*)d_in[0];
  const float* W1    = (const float*)d_in[1];
  const float* b1    = (const float*)d_in[2];
  const float* Wred  = (const float*)d_in[3];
  const float* bred  = (const float*)d_in[4];
  const float* Wspan = (const float*)d_in[5];
  const float* bspan = (const float*)d_in[6];
  const float* W2    = (const float*)d_in[7];
  const float* b2    = (const float*)d_in[8];
  const float* Weca  = (const float*)d_in[9];

  ushort_t* shuf    = (ushort_t*)d_ws;                        // 64 MiB records
  float*    gate    = (float*)((char*)d_ws + 67108864);       // 512 B
  ushort_t* wpack   = (ushort_t*)((char*)d_ws + 67108864 + 1024); // 18.4 KiB
  float*    scratch = (float*)d_out;  // 2048*16 floats; overwritten by k5

  k0_pack<<<9, 128, 0, stream>>>(W2, wpack);
  k12c   <<<2048, 256, 0, stream>>>(x, W1, b1, Wred, bred, Wspan, bspan, shuf);
  k3_conv2<<<2048, 256, 0, stream>>>(shuf, wpack, b2, scratch);
  k4_gate<<<8, 256, 0, stream>>>(scratch, Weca, gate);
  k5_scale<<<8192, 256, 0, stream>>>((const f32x4*)x, gate, (f32x4*)d_out);
}

// Round 14
// 85.381 us; speedup vs baseline: 1.1757x; 1.1757x over previous
//
#include <hip/hip_runtime.h>
#include <hip/hip_bf16.h>

#define H 256
#define Wd 256
#define H2 128

typedef unsigned short ushort_t;
typedef __attribute__((ext_vector_type(8))) short short8;
typedef __attribute__((ext_vector_type(4))) float f32x4;
typedef __attribute__((ext_vector_type(2))) float f32x2;

// guarded mish (k3: conv2 outputs can be large; keep the clamp)
__device__ __forceinline__ float mishf(float v){
  if (v > 15.f) return v;
  float e = __expf(v);
  float w = e*(e+2.f);
  return v * w * __builtin_amdgcn_rcpf(w + 2.f);
}
// slim mish (k12: conv1 outputs bounded |s|<~6 -> no overflow; branch-free)
__device__ __forceinline__ float mish_s(float v){
  float e = __expf(v);
  float w = e*(e+2.f);
  return v * w * __builtin_amdgcn_rcpf(w + 2.f);
}

__device__ __forceinline__ ushort_t f2bf(float f){
  unsigned int u = __float_as_uint(f);
  u += 0x7fffu + ((u >> 16) & 1u);
  return (ushort_t)(u >> 16);
}
__device__ __forceinline__ float bf2f(ushort_t h){
  return __uint_as_float(((unsigned int)h) << 16);
}
__device__ __forceinline__ unsigned packbf(float a, float b){
  return (unsigned)f2bf(a) | ((unsigned)f2bf(b) << 16);
}
__device__ __forceinline__ float lo16(unsigned u){
  return __uint_as_float(u << 16);
}
__device__ __forceinline__ float hi16(unsigned u){
  return __uint_as_float(u & 0xffff0000u);
}

// All-pair VOP3P FMAs. acc.{lo,hi} += f.{lo,hi} * broadcast(w.lo or w.hi).
__device__ __forceinline__ void pk_lo(f32x2 &acc, f32x2 f, f32x2 w){
  asm("v_pk_fma_f32 %0, %1, %2, %0 op_sel_hi:[1,0,1]"
      : "+v"(acc) : "v"(f), "v"(w));
}
__device__ __forceinline__ void pk_hi(f32x2 &acc, f32x2 f, f32x2 w){
  asm("v_pk_fma_f32 %0, %1, %2, %0 op_sel:[0,1,0] op_sel_hi:[1,1,1]"
      : "+v"(acc) : "v"(f), "v"(w));
}

// ---------------------------------------------------------------------------
// shuf layout: 8-byte pixel records  [plane = b*16 + c][i*256 + j][m0..3]
// (bf16 x4). k12 writes top rows (own plane) and bottom rows (rolled plane).
// ---------------------------------------------------------------------------

// K0: pre-pack W2 into bf16 MFMA A-fragment order.
__global__ void k0_pack(const float* __restrict__ W2, ushort_t* __restrict__ wpack)
{
  int idx = blockIdx.x*128 + threadIdx.x;   // 0..1151
  if (idx >= 1152) return;
  int lane  = idx & 63;
  int s     = (idx >> 6) % 9;
  int khalf = idx / 576;
  int n = lane & 15, g = lane >> 4;
  unsigned int w[4];
#pragma unroll
  for (int h = 0; h < 4; ++h){
    int ch0 = khalf*32 + g*8 + 2*h;
    unsigned lo = f2bf(W2[(n*64 + ch0  )*9 + s]);
    unsigned hi = f2bf(W2[(n*64 + ch0+1)*9 + s]);
    w[h] = lo | (hi << 16);
  }
  *(uint4*)(wpack + (size_t)idx*8) = make_uint4(w[0], w[1], w[2], w[3]);
}

// ---------------------------------------------------------------------------
// K12: fused conv1 top+bottom for one (plane, 16x64 tile).  [r8 structure]
// ft phase & f_bot: pixel-pair v_pk_fma accumulation; span: m-pair.
// LDS 20.4 KB (strides 71 / 67 -> <=2-way banks). 2 barriers.
// ---------------------------------------------------------------------------
__global__ __launch_bounds__(256,4) void k12(
    const float* __restrict__ x, const float* __restrict__ W1,
    const float* __restrict__ b1, const float* __restrict__ Wred,
    const float* __restrict__ bred, const float* __restrict__ Wspan,
    const float* __restrict__ bspan, ushort_t* __restrict__ shuf)
{
  __shared__ float xt[20][71];       // x rows itop0-2..+17, cols j0-4..j0+66
  __shared__ float xb[18][71];       // x rows 127+itop0..+17, cols j0-4..j0+66
  __shared__ unsigned ftp[2][18][67];// packed bf16 (m0|m1),(m2|m3)

  int bid = blockIdx.x;             // 128 planes * 8 rowtiles * 4 coltiles
  int n   = bid >> 5;
  int t   = bid & 31;
  int itop0 = (t >> 2) * 16;
  int j0    = (t & 3) * 64;
  int tid = threadIdx.x;
  const float* xp = x + (size_t)n * (H*Wd);

  f32x2 w01[9], w23[9], wspb[9];
  f32x2 bsp0, bsp1, bsp2, bsp3;
  float wredr[4];
  float bredr = bred[0];
#pragma unroll
  for (int k=0;k<9;k++){
    w01[k] = f32x2{W1[k], W1[9+k]};
    w23[k] = f32x2{W1[18+k], W1[27+k]};
    wspb[k] = f32x2{Wspan[k], bspan[k]};
  }
  bsp0 = f32x2{b1[0], b1[0]};
  bsp1 = f32x2{b1[1], b1[1]};
  bsp2 = f32x2{b1[2], b1[2]};
  bsp3 = f32x2{b1[3], b1[3]};
#pragma unroll
  for (int m=0;m<4;m++) wredr[m] = Wred[m];

  // ---- stage x_top: 20 rows x 18 float4 (cols j0-4 .. j0+67) ----
  for (int idx=tid; idx<360; idx+=256){
    int r = idx/18, q = idx - r*18;
    int grow = itop0-2+r, gcol = j0-4+q*4;
    float4 v = make_float4(0.f,0.f,0.f,0.f);
    if (grow>=0 && gcol>=0 && gcol<Wd)
      v = *(const float4*)(xp + (size_t)grow*Wd + gcol);
    int c0 = q*4;
    xt[r][c0] = v.x; xt[r][c0+1] = v.y; xt[r][c0+2] = v.z;
    if (c0+3 < 71) xt[r][c0+3] = v.w;
  }
  // ---- stage x_bot: 18 rows x 18 float4 ----
  for (int idx=tid; idx<324; idx+=256){
    int r = idx/18, q = idx - r*18;
    int grow = 127+itop0+r, gcol = j0-4+q*4;
    float4 v = make_float4(0.f,0.f,0.f,0.f);
    if (grow<H && gcol>=0 && gcol<Wd)
      v = *(const float4*)(xp + (size_t)grow*Wd + gcol);
    int c0 = q*4;
    xb[r][c0] = v.x; xb[r][c0+1] = v.y; xb[r][c0+2] = v.z;
    if (c0+3 < 71) xb[r][c0+3] = v.w;
  }
  __syncthreads();

  // ---- f_top -> packed bf16 LDS; pixel-pair accumulation (18 x 33 pairs) ----
  for (int idx=tid; idx<594; idx+=256){
    int r = idx/33, cp = idx - r*33;
    int c = cp*2;                   // elem col in [0,66)
    f32x2 sm0=bsp0, sm1=bsp1, sm2=bsp2, sm3=bsp3;
#pragma unroll
    for (int ky=0;ky<3;ky++){
      float x0 = xt[r+ky][c+2], x1 = xt[r+ky][c+3];
      float x2 = xt[r+ky][c+4], x3 = xt[r+ky][c+5];
      f32x2 p0 = f32x2{x0,x1}, p1 = f32x2{x1,x2}, p2 = f32x2{x2,x3};
      f32x2 wa0 = w01[ky*3], wa1 = w01[ky*3+1], wa2 = w01[ky*3+2];
      f32x2 wb0 = w23[ky*3], wb1 = w23[ky*3+1], wb2 = w23[ky*3+2];
      pk_lo(sm0,p0,wa0); pk_hi(sm1,p0,wa0); pk_lo(sm2,p0,wb0); pk_hi(sm3,p0,wb0);
      pk_lo(sm0,p1,wa1); pk_hi(sm1,p1,wa1); pk_lo(sm2,p1,wb1); pk_hi(sm3,p1,wb1);
      pk_lo(sm0,p2,wa2); pk_hi(sm1,p2,wa2); pk_lo(sm2,p2,wb2); pk_hi(sm3,p2,wb2);
    }
    int frow = itop0-1+r;
    int fc0  = j0-1+c;
    bool rok = (frow>=0) && (frow<H2);
    bool ok0 = rok && (fc0>=0) && (fc0<Wd);
    bool ok1 = rok && (fc0+1<Wd);
    ftp[0][r][c]   = ok0 ? packbf(mish_s(sm0.x), mish_s(sm1.x)) : 0u;
    ftp[1][r][c]   = ok0 ? packbf(mish_s(sm2.x), mish_s(sm3.x)) : 0u;
    ftp[0][r][c+1] = ok1 ? packbf(mish_s(sm0.y), mish_s(sm1.y)) : 0u;
    ftp[1][r][c+1] = ok1 ? packbf(mish_s(sm2.y), mish_s(sm3.y)) : 0u;
  }

  int lr  = tid >> 4;
  int lc4 = (tid & 15) * 4;
  int trow = itop0 + lr;
  int bq = n >> 4, cq = n & 15;

  // ---- f_bot own 4 px, pixel-pair: sA* = px(0,1), sB* = px(2,3) ----
  f32x2 xq[3][5];
#pragma unroll
  for (int r=0;r<3;r++)
#pragma unroll
    for (int c2=0;c2<5;c2++)
      xq[r][c2] = f32x2{xb[lr+r][lc4+3+c2], xb[lr+r][lc4+4+c2]};

  f32x2 sA0=bsp0,sA1=bsp1,sA2=bsp2,sA3=bsp3;
  f32x2 sB0=bsp0,sB1=bsp1,sB2=bsp2,sB3=bsp3;
#pragma unroll
  for (int ky=0;ky<3;ky++)
#pragma unroll
    for (int kx=0;kx<3;kx++){
      f32x2 w0 = w01[ky*3+kx], w2 = w23[ky*3+kx];
      f32x2 qa = xq[ky][kx], qb = xq[ky][kx+2];
      pk_lo(sA0, qa, w0); pk_hi(sA1, qa, w0);
      pk_lo(sA2, qa, w2); pk_hi(sA3, qa, w2);
      pk_lo(sB0, qb, w0); pk_hi(sB1, qb, w0);
      pk_lo(sB2, qb, w2); pk_hi(sB3, qb, w2);
    }
  float fb[4][4];
  fb[0][0]=mish_s(sA0.x); fb[0][1]=mish_s(sA0.y); fb[0][2]=mish_s(sB0.x); fb[0][3]=mish_s(sB0.y);
  fb[1][0]=mish_s(sA1.x); fb[1][1]=mish_s(sA1.y); fb[1][2]=mish_s(sB1.x); fb[1][3]=mish_s(sB1.y);
  fb[2][0]=mish_s(sA2.x); fb[2][1]=mish_s(sA2.y); fb[2][2]=mish_s(sB2.x); fb[2][3]=mish_s(sB2.y);
  fb[3][0]=mish_s(sA3.x); fb[3][1]=mish_s(sA3.y); fb[3][2]=mish_s(sB3.x); fb[3][3]=mish_s(sB3.y);

  // bottom store (rolled plane), 2 px per dwordx4
  int cdst = (cq + 15) & 15;
  size_t bbase = ((size_t)(bq*16 + cdst))*65536 + (size_t)(128+trow)*256 + j0 + lc4;
  {
    unsigned w0 = packbf(fb[0][0], fb[1][0]), w1 = packbf(fb[2][0], fb[3][0]);
    unsigned w2 = packbf(fb[0][1], fb[1][1]), w3 = packbf(fb[2][1], fb[3][1]);
    *(uint4*)(shuf + bbase*4) = make_uint4(w0,w1,w2,w3);
    unsigned w4 = packbf(fb[0][2], fb[1][2]), w5 = packbf(fb[2][2], fb[3][2]);
    unsigned w6 = packbf(fb[0][3], fb[1][3]), w7 = packbf(fb[2][3], fb[3][3]);
    *(uint4*)(shuf + (bbase+2)*4) = make_uint4(w4,w5,w6,w7);
  }
  float gv[4];
#pragma unroll
  for (int p=0;p<4;p++){
    float s = bredr;
#pragma unroll
    for (int m=0;m<4;m++) s = fmaf(fb[m][p], wredr[m], s);
    gv[p] = fmaxf(s, 0.f);
  }

  __syncthreads();

  // ---- span convs: m-pair accumulation straight from packed words ----
  f32x2 pA01[4], pB01[4], pA23[4], pB23[4];
#pragma unroll
  for (int p=0;p<4;p++){
    pA01[p] = f32x2{0.f,0.f}; pB01[p] = f32x2{0.f,0.f};
    pA23[p] = f32x2{0.f,0.f}; pB23[p] = f32x2{0.f,0.f};
  }
#pragma unroll
  for (int ky=0;ky<3;ky++){
    f32x2 fm01[6], fm23[6];
#pragma unroll
    for (int c2=0;c2<6;c2++){
      unsigned u0 = ftp[0][lr+ky][lc4+c2];
      unsigned u1 = ftp[1][lr+ky][lc4+c2];
      fm01[c2] = f32x2{lo16(u0), hi16(u0)};
      fm23[c2] = f32x2{lo16(u1), hi16(u1)};
    }
#pragma unroll
    for (int kx=0;kx<3;kx++){
      f32x2 w = wspb[ky*3+kx];
#pragma unroll
      for (int p=0;p<4;p++){
        pk_lo(pA01[p], fm01[p+kx], w);
        pk_hi(pB01[p], fm01[p+kx], w);
        pk_lo(pA23[p], fm23[p+kx], w);
        pk_hi(pB23[p], fm23[p+kx], w);
      }
    }
  }
  float o[4][4];
#pragma unroll
  for (int p=0;p<4;p++){
    o[0][p] = fmaf(gv[p], pA01[p].x, pB01[p].x);
    o[1][p] = fmaf(gv[p], pA01[p].y, pB01[p].y);
    o[2][p] = fmaf(gv[p], pA23[p].x, pB23[p].x);
    o[3][p] = fmaf(gv[p], pA23[p].y, pB23[p].y);
  }
  size_t pbase = ((size_t)(bq*16 + cq))*65536 + (size_t)trow*256 + j0 + lc4;
  {
    unsigned w0 = packbf(o[0][0], o[1][0]), w1 = packbf(o[2][0], o[3][0]);
    unsigned w2 = packbf(o[0][1], o[1][1]), w3 = packbf(o[2][1], o[3][1]);
    *(uint4*)(shuf + pbase*4) = make_uint4(w0,w1,w2,w3);
    unsigned w4 = packbf(o[0][2], o[1][2]), w5 = packbf(o[2][2], o[3][2]);
    unsigned w6 = packbf(o[0][3], o[1][3]), w7 = packbf(o[2][3], o[3][3]);
    *(uint4*)(shuf + (pbase+2)*4) = make_uint4(w4,w5,w6,w7);
  }
}

// ---------------------------------------------------------------------------
// K3: conv2 via MFMA implicit GEMM, direct-from-global B fragments.
// ---------------------------------------------------------------------------
__global__ __launch_bounds__(256) void k3_conv2(
    const ushort_t* __restrict__ shuf, const ushort_t* __restrict__ wpack,
    const float* __restrict__ b2, float* __restrict__ scratch)
{
  __shared__ f32x4 mg[2][8][64];   // 16 KiB
  __shared__ float pacc[16];

  int bid0 = blockIdx.x;                     // 2048
  int bid  = (bid0 & 7)*256 + (bid0 >> 3);   // XCD-contiguous chunks
  int b   = bid >> 8;
  int t   = bid & 255;
  int rb  = t >> 3;
  int cb  = t & 7;
  int tid = threadIdx.x;
  int lane = tid & 63;
  int n = lane & 15;
  int g = lane >> 4;
  int wid = tid >> 6;
  int colhalf = wid & 1;
  int khalf   = wid >> 1;

  if (tid < 16) pacc[tid] = 0.f;

  const short8* wp = (const short8*)wpack + (size_t)khalf*576 + lane;
  short8 afr[9];
#pragma unroll
  for (int s = 0; s < 9; ++s) afr[s] = wp[s*64];

  f32x4 acc[8];
#pragma unroll
  for (int r = 0; r < 8; ++r) acc[r] = f32x4{0.f,0.f,0.f,0.f};

  int r0 = rb*8 - 1;
  int c  = cb*32 - 1 + colhalf*16 + n;
  int p0 = khalf*8 + g*2;
  const ushort_t* sp = shuf + ((size_t)(b*16 + p0))*262144;

#pragma unroll
  for (int hr = 0; hr < 10; ++hr){
    int grow = r0 + hr;
    bool rok = (unsigned)grow < 256u;
    uint2 va[3], vbv[3];
#pragma unroll
    for (int kx = 0; kx < 3; ++kx){
      int gcol = c + kx;
      uint2 a = make_uint2(0u,0u), bv = make_uint2(0u,0u);
      if (rok && (unsigned)gcol < 256u){
        const ushort_t* pp = sp + (size_t)(grow*256 + gcol)*4;
        a  = *(const uint2*)pp;
        bv = *(const uint2*)(pp + 262144);
      }
      va[kx] = a; vbv[kx] = bv;
    }
#pragma unroll
    for (int kx = 0; kx < 3; ++kx){
      union { uint4 u; short8 s; } cv;
      cv.u = make_uint4(va[kx].x, va[kx].y, vbv[kx].x, vbv[kx].y);
#pragma unroll
      for (int ky = 0; ky < 3; ++ky){
        int orow = hr - ky;
        if (orow >= 0 && orow < 8){
          acc[orow] = __builtin_amdgcn_mfma_f32_16x16x32_bf16(
              afr[ky*3+kx], cv.s, acc[orow], 0, 0, 0);
        }
      }
    }
  }

  if (khalf == 1){
#pragma unroll
    for (int r = 0; r < 8; ++r) mg[colhalf][r][lane] = acc[r];
  }
  __syncthreads();

  if (khalf == 0){
    float b2v[4];
#pragma unroll
    for (int q = 0; q < 4; ++q) b2v[q] = b2[g*4 + q];
    float po[4] = {0.f, 0.f, 0.f, 0.f};
#pragma unroll
    for (int r = 0; r < 8; ++r){
      f32x4 o = acc[r] + mg[colhalf][r][lane];
#pragma unroll
      for (int q = 0; q < 4; ++q) po[q] += mishf(o[q] + b2v[q]);
    }
#pragma unroll
    for (int q = 0; q < 4; ++q){
#pragma unroll
      for (int mk = 1; mk < 16; mk <<= 1) po[q] += __shfl_xor(po[q], mk);
    }
    if (n == 0){
#pragma unroll
      for (int q = 0; q < 4; ++q) atomicAdd(&pacc[g*4 + q], po[q]);
    }
  }
  __syncthreads();
  if (tid < 16) scratch[bid*16 + tid] = pacc[tid];
}

// K4: reduce per-block partials -> pooled mean -> ECA gate. One block per b.
__global__ void k4_gate(const float* __restrict__ scratch,
                        const float* __restrict__ Weca,
                        float* __restrict__ gate)
{
  __shared__ float rr[16][16];
  __shared__ float pool[16];
  int b = blockIdx.x;
  int t = threadIdx.x;           // 256
  int oc = t & 15, ch = t >> 4;
  float s = 0.f;
  for (int u = 0; u < 16; ++u)
    s += scratch[(size_t)(b*256 + ch*16 + u)*16 + oc];
  rr[ch][oc] = s;
  __syncthreads();
  if (t < 16){
    float tot = 0.f;
#pragma unroll
    for (int k = 0; k < 16; ++k) tot += rr[k][t];
    pool[t] = tot * (1.0f/65536.0f);
  }
  __syncthreads();
  if (t < 16){
    float pm = (t > 0)  ? pool[t-1] : 0.f;
    float p0 = pool[t];
    float pp = (t < 15) ? pool[t+1] : 0.f;
    float z = Weca[0]*pm + Weca[1]*p0 + Weca[2]*pp;
    gate[b*16 + t] = 1.f/(1.f + __expf(-z));
  }
}

// K5: out = x * gate[b,c], nontemporal load+store
__global__ __launch_bounds__(256) void k5_scale(
    const f32x4* __restrict__ x4, const float* __restrict__ gate,
    f32x4* __restrict__ out4)
{
  int idx = blockIdx.x*256 + threadIdx.x;
  float g = gate[idx >> 14];
  f32x4 v = __builtin_nontemporal_load(&x4[idx]) * g;
  __builtin_nontemporal_store(v, &out4[idx]);
}

extern "C" void kernel_launch(void* const* d_in, const int* in_sizes, int n_in,
                              void* d_out, int out_size, void* d_ws, size_t ws_size,
                              hipStream_t stream)
{
  const float* x     = (const float*)d_in[0];
  const float* W1    = (const float*)d_in[1];
  const float* b1    = (const float*)d_in[2];
  const float* Wred  = (const float*)d_in[3];
  const float* bred  = (const float*)d_in[4];
  const float* Wspan = (const float*)d_in[5];
  const float* bspan = (const float*)d_in[6];
  const float* W2    = (const float*)d_in[7];
  const float* b2    = (const float*)d_in[8];
  const float* Weca  = (const float*)d_in[9];

  ushort_t* shuf    = (ushort_t*)d_ws;                        // 64 MiB records
  float*    gate    = (float*)((char*)d_ws + 67108864);       // 512 B
  ushort_t* wpack   = (ushort_t*)((char*)d_ws + 67108864 + 1024); // 18.4 KiB
  float*    scratch = (float*)d_out;  // 2048*16 floats; overwritten by k5

  k0_pack<<<9, 128, 0, stream>>>(W2, wpack);
  k12    <<<4096, 256, 0, stream>>>(x, W1, b1, Wred, bred, Wspan, bspan, shuf);
  k3_conv2<<<2048, 256, 0, stream>>>(shuf, wpack, b2, scratch);
  k4_gate<<<8, 256, 0, stream>>>(scratch, Weca, gate);
  k5_scale<<<8192, 256, 0, stream>>>((const f32x4*)x, gate, (f32x4*)d_out);
}

// Round 15
// 82.647 us; speedup vs baseline: 1.2145x; 1.0331x over previous
//
#include <hip/hip_runtime.h>
#include <hip/hip_bf16.h>

#define H 256
#define Wd 256
#define H2 128

typedef unsigned short ushort_t;
typedef __attribute__((ext_vector_type(8))) short short8;
typedef __attribute__((ext_vector_type(4))) float f32x4;
typedef __attribute__((ext_vector_type(2))) float f32x2;

// guarded mish (k3: conv2 outputs can be large; keep the clamp)
__device__ __forceinline__ float mishf(float v){
  if (v > 15.f) return v;
  float e = __expf(v);
  float w = e*(e+2.f);
  return v * w * __builtin_amdgcn_rcpf(w + 2.f);
}
// slim mish (k12: conv1 outputs bounded |s|<~6 -> no overflow; branch-free)
__device__ __forceinline__ float mish_s(float v){
  float e = __expf(v);
  float w = e*(e+2.f);
  return v * w * __builtin_amdgcn_rcpf(w + 2.f);
}

__device__ __forceinline__ ushort_t f2bf(float f){
  unsigned int u = __float_as_uint(f);
  u += 0x7fffu + ((u >> 16) & 1u);
  return (ushort_t)(u >> 16);
}
__device__ __forceinline__ float bf2f(ushort_t h){
  return __uint_as_float(((unsigned int)h) << 16);
}
__device__ __forceinline__ unsigned packbf(float a, float b){
  return (unsigned)f2bf(a) | ((unsigned)f2bf(b) << 16);
}
__device__ __forceinline__ float lo16(unsigned u){
  return __uint_as_float(u << 16);
}
__device__ __forceinline__ float hi16(unsigned u){
  return __uint_as_float(u & 0xffff0000u);
}

// All-pair VOP3P FMAs. acc.{lo,hi} += f.{lo,hi} * broadcast(w.lo or w.hi).
__device__ __forceinline__ void pk_lo(f32x2 &acc, f32x2 f, f32x2 w){
  asm("v_pk_fma_f32 %0, %1, %2, %0 op_sel_hi:[1,0,1]"
      : "+v"(acc) : "v"(f), "v"(w));
}
__device__ __forceinline__ void pk_hi(f32x2 &acc, f32x2 f, f32x2 w){
  asm("v_pk_fma_f32 %0, %1, %2, %0 op_sel:[0,1,0] op_sel_hi:[1,1,1]"
      : "+v"(acc) : "v"(f), "v"(w));
}

// ---------------------------------------------------------------------------
// shuf layout: 8-byte pixel records  [plane = b*16 + c][i*256 + j][m0..3]
// (bf16 x4). k12 writes top rows (own plane) and bottom rows (rolled plane).
// ---------------------------------------------------------------------------

// K0: pre-pack W2 into bf16 MFMA A-fragment order.
__global__ void k0_pack(const float* __restrict__ W2, ushort_t* __restrict__ wpack)
{
  int idx = blockIdx.x*128 + threadIdx.x;   // 0..1151
  if (idx >= 1152) return;
  int lane  = idx & 63;
  int s     = (idx >> 6) % 9;
  int khalf = idx / 576;
  int n = lane & 15, g = lane >> 4;
  unsigned int w[4];
#pragma unroll
  for (int h = 0; h < 4; ++h){
    int ch0 = khalf*32 + g*8 + 2*h;
    unsigned lo = f2bf(W2[(n*64 + ch0  )*9 + s]);
    unsigned hi = f2bf(W2[(n*64 + ch0+1)*9 + s]);
    w[h] = lo | (hi << 16);
  }
  *(uint4*)(wpack + (size_t)idx*8) = make_uint4(w[0], w[1], w[2], w[3]);
}

// ---------------------------------------------------------------------------
// K12: fused conv1 top+bottom for one (plane, 16x64 tile).  [r8 structure]
// ft phase & f_bot: pixel-pair v_pk_fma accumulation; span: m-pair.
// LDS 20.4 KB (strides 71 / 67 -> <=2-way banks). 2 barriers.
// Grid XCD-chunked: XCD x owns batch b=x (512 contiguous bids = 16 planes),
// so rolled-plane bottom stores stay in the writing XCD's L2 and k3 (which
// maps batch b -> XCD b) rereads warm lines.
// ---------------------------------------------------------------------------
__global__ __launch_bounds__(256,4) void k12(
    const float* __restrict__ x, const float* __restrict__ W1,
    const float* __restrict__ b1, const float* __restrict__ Wred,
    const float* __restrict__ bred, const float* __restrict__ Wspan,
    const float* __restrict__ bspan, ushort_t* __restrict__ shuf)
{
  __shared__ float xt[20][71];       // x rows itop0-2..+17, cols j0-4..j0+66
  __shared__ float xb[18][71];       // x rows 127+itop0..+17, cols j0-4..j0+66
  __shared__ unsigned ftp[2][18][67];// packed bf16 (m0|m1),(m2|m3)

  int bid0 = blockIdx.x;                    // 4096
  int bid  = (bid0 & 7)*512 + (bid0 >> 3);  // XCD x -> bids [512x,512x+512) = batch x
  int n   = bid >> 5;
  int t   = bid & 31;
  int itop0 = (t >> 2) * 16;
  int j0    = (t & 3) * 64;
  int tid = threadIdx.x;
  const float* xp = x + (size_t)n * (H*Wd);

  f32x2 w01[9], w23[9], wspb[9];
  f32x2 bsp0, bsp1, bsp2, bsp3;
  float wredr[4];
  float bredr = bred[0];
#pragma unroll
  for (int k=0;k<9;k++){
    w01[k] = f32x2{W1[k], W1[9+k]};
    w23[k] = f32x2{W1[18+k], W1[27+k]};
    wspb[k] = f32x2{Wspan[k], bspan[k]};
  }
  bsp0 = f32x2{b1[0], b1[0]};
  bsp1 = f32x2{b1[1], b1[1]};
  bsp2 = f32x2{b1[2], b1[2]};
  bsp3 = f32x2{b1[3], b1[3]};
#pragma unroll
  for (int m=0;m<4;m++) wredr[m] = Wred[m];

  // ---- stage x_top: 20 rows x 18 float4 (cols j0-4 .. j0+67) ----
  for (int idx=tid; idx<360; idx+=256){
    int r = idx/18, q = idx - r*18;
    int grow = itop0-2+r, gcol = j0-4+q*4;
    float4 v = make_float4(0.f,0.f,0.f,0.f);
    if (grow>=0 && gcol>=0 && gcol<Wd)
      v = *(const float4*)(xp + (size_t)grow*Wd + gcol);
    int c0 = q*4;
    xt[r][c0] = v.x; xt[r][c0+1] = v.y; xt[r][c0+2] = v.z;
    if (c0+3 < 71) xt[r][c0+3] = v.w;
  }
  // ---- stage x_bot: 18 rows x 18 float4 ----
  for (int idx=tid; idx<324; idx+=256){
    int r = idx/18, q = idx - r*18;
    int grow = 127+itop0+r, gcol = j0-4+q*4;
    float4 v = make_float4(0.f,0.f,0.f,0.f);
    if (grow<H && gcol>=0 && gcol<Wd)
      v = *(const float4*)(xp + (size_t)grow*Wd + gcol);
    int c0 = q*4;
    xb[r][c0] = v.x; xb[r][c0+1] = v.y; xb[r][c0+2] = v.z;
    if (c0+3 < 71) xb[r][c0+3] = v.w;
  }
  __syncthreads();

  // ---- f_top -> packed bf16 LDS; pixel-pair accumulation (18 x 33 pairs) ----
  for (int idx=tid; idx<594; idx+=256){
    int r = idx/33, cp = idx - r*33;
    int c = cp*2;                   // elem col in [0,66)
    f32x2 sm0=bsp0, sm1=bsp1, sm2=bsp2, sm3=bsp3;
#pragma unroll
    for (int ky=0;ky<3;ky++){
      float x0 = xt[r+ky][c+2], x1 = xt[r+ky][c+3];
      float x2 = xt[r+ky][c+4], x3 = xt[r+ky][c+5];
      f32x2 p0 = f32x2{x0,x1}, p1 = f32x2{x1,x2}, p2 = f32x2{x2,x3};
      f32x2 wa0 = w01[ky*3], wa1 = w01[ky*3+1], wa2 = w01[ky*3+2];
      f32x2 wb0 = w23[ky*3], wb1 = w23[ky*3+1], wb2 = w23[ky*3+2];
      pk_lo(sm0,p0,wa0); pk_hi(sm1,p0,wa0); pk_lo(sm2,p0,wb0); pk_hi(sm3,p0,wb0);
      pk_lo(sm0,p1,wa1); pk_hi(sm1,p1,wa1); pk_lo(sm2,p1,wb1); pk_hi(sm3,p1,wb1);
      pk_lo(sm0,p2,wa2); pk_hi(sm1,p2,wa2); pk_lo(sm2,p2,wb2); pk_hi(sm3,p2,wb2);
    }
    int frow = itop0-1+r;
    int fc0  = j0-1+c;
    bool rok = (frow>=0) && (frow<H2);
    bool ok0 = rok && (fc0>=0) && (fc0<Wd);
    bool ok1 = rok && (fc0+1<Wd);
    ftp[0][r][c]   = ok0 ? packbf(mish_s(sm0.x), mish_s(sm1.x)) : 0u;
    ftp[1][r][c]   = ok0 ? packbf(mish_s(sm2.x), mish_s(sm3.x)) : 0u;
    ftp[0][r][c+1] = ok1 ? packbf(mish_s(sm0.y), mish_s(sm1.y)) : 0u;
    ftp[1][r][c+1] = ok1 ? packbf(mish_s(sm2.y), mish_s(sm3.y)) : 0u;
  }

  int lr  = tid >> 4;
  int lc4 = (tid & 15) * 4;
  int trow = itop0 + lr;
  int bq = n >> 4, cq = n & 15;

  // ---- f_bot own 4 px, pixel-pair: sA* = px(0,1), sB* = px(2,3) ----
  f32x2 xq[3][5];
#pragma unroll
  for (int r=0;r<3;r++)
#pragma unroll
    for (int c2=0;c2<5;c2++)
      xq[r][c2] = f32x2{xb[lr+r][lc4+3+c2], xb[lr+r][lc4+4+c2]};

  f32x2 sA0=bsp0,sA1=bsp1,sA2=bsp2,sA3=bsp3;
  f32x2 sB0=bsp0,sB1=bsp1,sB2=bsp2,sB3=bsp3;
#pragma unroll
  for (int ky=0;ky<3;ky++)
#pragma unroll
    for (int kx=0;kx<3;kx++){
      f32x2 w0 = w01[ky*3+kx], w2 = w23[ky*3+kx];
      f32x2 qa = xq[ky][kx], qb = xq[ky][kx+2];
      pk_lo(sA0, qa, w0); pk_hi(sA1, qa, w0);
      pk_lo(sA2, qa, w2); pk_hi(sA3, qa, w2);
      pk_lo(sB0, qb, w0); pk_hi(sB1, qb, w0);
      pk_lo(sB2, qb, w2); pk_hi(sB3, qb, w2);
    }
  float fb[4][4];
  fb[0][0]=mish_s(sA0.x); fb[0][1]=mish_s(sA0.y); fb[0][2]=mish_s(sB0.x); fb[0][3]=mish_s(sB0.y);
  fb[1][0]=mish_s(sA1.x); fb[1][1]=mish_s(sA1.y); fb[1][2]=mish_s(sB1.x); fb[1][3]=mish_s(sB1.y);
  fb[2][0]=mish_s(sA2.x); fb[2][1]=mish_s(sA2.y); fb[2][2]=mish_s(sB2.x); fb[2][3]=mish_s(sB2.y);
  fb[3][0]=mish_s(sA3.x); fb[3][1]=mish_s(sA3.y); fb[3][2]=mish_s(sB3.x); fb[3][3]=mish_s(sB3.y);

  // bottom store (rolled plane, same batch -> same XCD L2), 2 px per dwordx4
  int cdst = (cq + 15) & 15;
  size_t bbase = ((size_t)(bq*16 + cdst))*65536 + (size_t)(128+trow)*256 + j0 + lc4;
  {
    unsigned w0 = packbf(fb[0][0], fb[1][0]), w1 = packbf(fb[2][0], fb[3][0]);
    unsigned w2 = packbf(fb[0][1], fb[1][1]), w3 = packbf(fb[2][1], fb[3][1]);
    *(uint4*)(shuf + bbase*4) = make_uint4(w0,w1,w2,w3);
    unsigned w4 = packbf(fb[0][2], fb[1][2]), w5 = packbf(fb[2][2], fb[3][2]);
    unsigned w6 = packbf(fb[0][3], fb[1][3]), w7 = packbf(fb[2][3], fb[3][3]);
    *(uint4*)(shuf + (bbase+2)*4) = make_uint4(w4,w5,w6,w7);
  }
  float gv[4];
#pragma unroll
  for (int p=0;p<4;p++){
    float s = bredr;
#pragma unroll
    for (int m=0;m<4;m++) s = fmaf(fb[m][p], wredr[m], s);
    gv[p] = fmaxf(s, 0.f);
  }

  __syncthreads();

  // ---- span convs: m-pair accumulation straight from packed words ----
  f32x2 pA01[4], pB01[4], pA23[4], pB23[4];
#pragma unroll
  for (int p=0;p<4;p++){
    pA01[p] = f32x2{0.f,0.f}; pB01[p] = f32x2{0.f,0.f};
    pA23[p] = f32x2{0.f,0.f}; pB23[p] = f32x2{0.f,0.f};
  }
#pragma unroll
  for (int ky=0;ky<3;ky++){
    f32x2 fm01[6], fm23[6];
#pragma unroll
    for (int c2=0;c2<6;c2++){
      unsigned u0 = ftp[0][lr+ky][lc4+c2];
      unsigned u1 = ftp[1][lr+ky][lc4+c2];
      fm01[c2] = f32x2{lo16(u0), hi16(u0)};
      fm23[c2] = f32x2{lo16(u1), hi16(u1)};
    }
#pragma unroll
    for (int kx=0;kx<3;kx++){
      f32x2 w = wspb[ky*3+kx];
#pragma unroll
      for (int p=0;p<4;p++){
        pk_lo(pA01[p], fm01[p+kx], w);
        pk_hi(pB01[p], fm01[p+kx], w);
        pk_lo(pA23[p], fm23[p+kx], w);
        pk_hi(pB23[p], fm23[p+kx], w);
      }
    }
  }
  float o[4][4];
#pragma unroll
  for (int p=0;p<4;p++){
    o[0][p] = fmaf(gv[p], pA01[p].x, pB01[p].x);
    o[1][p] = fmaf(gv[p], pA01[p].y, pB01[p].y);
    o[2][p] = fmaf(gv[p], pA23[p].x, pB23[p].x);
    o[3][p] = fmaf(gv[p], pA23[p].y, pB23[p].y);
  }
  size_t pbase = ((size_t)(bq*16 + cq))*65536 + (size_t)trow*256 + j0 + lc4;
  {
    unsigned w0 = packbf(o[0][0], o[1][0]), w1 = packbf(o[2][0], o[3][0]);
    unsigned w2 = packbf(o[0][1], o[1][1]), w3 = packbf(o[2][1], o[3][1]);
    *(uint4*)(shuf + pbase*4) = make_uint4(w0,w1,w2,w3);
    unsigned w4 = packbf(o[0][2], o[1][2]), w5 = packbf(o[2][2], o[3][2]);
    unsigned w6 = packbf(o[0][3], o[1][3]), w7 = packbf(o[2][3], o[3][3]);
    *(uint4*)(shuf + (pbase+2)*4) = make_uint4(w4,w5,w6,w7);
  }
}

// ---------------------------------------------------------------------------
// K3: conv2 via MFMA implicit GEMM, direct-from-global B fragments.
// ---------------------------------------------------------------------------
__global__ __launch_bounds__(256) void k3_conv2(
    const ushort_t* __restrict__ shuf, const ushort_t* __restrict__ wpack,
    const float* __restrict__ b2, float* __restrict__ scratch)
{
  __shared__ f32x4 mg[2][8][64];   // 16 KiB
  __shared__ float pacc[16];

  int bid0 = blockIdx.x;                     // 2048
  int bid  = (bid0 & 7)*256 + (bid0 >> 3);   // XCD x -> batch x (matches k12)
  int b   = bid >> 8;
  int t   = bid & 255;
  int rb  = t >> 3;
  int cb  = t & 7;
  int tid = threadIdx.x;
  int lane = tid & 63;
  int n = lane & 15;
  int g = lane >> 4;
  int wid = tid >> 6;
  int colhalf = wid & 1;
  int khalf   = wid >> 1;

  if (tid < 16) pacc[tid] = 0.f;

  const short8* wp = (const short8*)wpack + (size_t)khalf*576 + lane;
  short8 afr[9];
#pragma unroll
  for (int s = 0; s < 9; ++s) afr[s] = wp[s*64];

  f32x4 acc[8];
#pragma unroll
  for (int r = 0; r < 8; ++r) acc[r] = f32x4{0.f,0.f,0.f,0.f};

  int r0 = rb*8 - 1;
  int c  = cb*32 - 1 + colhalf*16 + n;
  int p0 = khalf*8 + g*2;
  const ushort_t* sp = shuf + ((size_t)(b*16 + p0))*262144;

#pragma unroll
  for (int hr = 0; hr < 10; ++hr){
    int grow = r0 + hr;
    bool rok = (unsigned)grow < 256u;
    uint2 va[3], vbv[3];
#pragma unroll
    for (int kx = 0; kx < 3; ++kx){
      int gcol = c + kx;
      uint2 a = make_uint2(0u,0u), bv = make_uint2(0u,0u);
      if (rok && (unsigned)gcol < 256u){
        const ushort_t* pp = sp + (size_t)(grow*256 + gcol)*4;
        a  = *(const uint2*)pp;
        bv = *(const uint2*)(pp + 262144);
      }
      va[kx] = a; vbv[kx] = bv;
    }
#pragma unroll
    for (int kx = 0; kx < 3; ++kx){
      union { uint4 u; short8 s; } cv;
      cv.u = make_uint4(va[kx].x, va[kx].y, vbv[kx].x, vbv[kx].y);
#pragma unroll
      for (int ky = 0; ky < 3; ++ky){
        int orow = hr - ky;
        if (orow >= 0 && orow < 8){
          acc[orow] = __builtin_amdgcn_mfma_f32_16x16x32_bf16(
              afr[ky*3+kx], cv.s, acc[orow], 0, 0, 0);
        }
      }
    }
  }

  if (khalf == 1){
#pragma unroll
    for (int r = 0; r < 8; ++r) mg[colhalf][r][lane] = acc[r];
  }
  __syncthreads();

  if (khalf == 0){
    float b2v[4];
#pragma unroll
    for (int q = 0; q < 4; ++q) b2v[q] = b2[g*4 + q];
    float po[4] = {0.f, 0.f, 0.f, 0.f};
#pragma unroll
    for (int r = 0; r < 8; ++r){
      f32x4 o = acc[r] + mg[colhalf][r][lane];
#pragma unroll
      for (int q = 0; q < 4; ++q) po[q] += mishf(o[q] + b2v[q]);
    }
#pragma unroll
    for (int q = 0; q < 4; ++q){
#pragma unroll
      for (int mk = 1; mk < 16; mk <<= 1) po[q] += __shfl_xor(po[q], mk);
    }
    if (n == 0){
#pragma unroll
      for (int q = 0; q < 4; ++q) atomicAdd(&pacc[g*4 + q], po[q]);
    }
  }
  __syncthreads();
  if (tid < 16) scratch[bid*16 + tid] = pacc[tid];
}

// K4: reduce per-block partials -> pooled mean -> ECA gate. One block per b.
__global__ void k4_gate(const float* __restrict__ scratch,
                        const float* __restrict__ Weca,
                        float* __restrict__ gate)
{
  __shared__ float rr[16][16];
  __shared__ float pool[16];
  int b = blockIdx.x;
  int t = threadIdx.x;           // 256
  int oc = t & 15, ch = t >> 4;
  float s = 0.f;
  for (int u = 0; u < 16; ++u)
    s += scratch[(size_t)(b*256 + ch*16 + u)*16 + oc];
  rr[ch][oc] = s;
  __syncthreads();
  if (t < 16){
    float tot = 0.f;
#pragma unroll
    for (int k = 0; k < 16; ++k) tot += rr[k][t];
    pool[t] = tot * (1.0f/65536.0f);
  }
  __syncthreads();
  if (t < 16){
    float pm = (t > 0)  ? pool[t-1] : 0.f;
    float p0 = pool[t];
    float pp = (t < 15) ? pool[t+1] : 0.f;
    float z = Weca[0]*pm + Weca[1]*p0 + Weca[2]*pp;
    gate[b*16 + t] = 1.f/(1.f + __expf(-z));
  }
}

// K5: out = x * gate[b,c]. Plain load (x may be L3-resident), nt store only.
__global__ __launch_bounds__(256) void k5_scale(
    const f32x4* __restrict__ x4, const float* __restrict__ gate,
    f32x4* __restrict__ out4)
{
  int idx = blockIdx.x*256 + threadIdx.x;
  float g = gate[idx >> 14];
  f32x4 v = x4[idx] * g;
  __builtin_nontemporal_store(v, &out4[idx]);
}

extern "C" void kernel_launch(void* const* d_in, const int* in_sizes, int n_in,
                              void* d_out, int out_size, void* d_ws, size_t ws_size,
                              hipStream_t stream)
{
  const float* x     = (const float*)d_in[0];
  const float* W1    = (const float*)d_in[1];
  const float* b1    = (const float*)d_in[2];
  const float* Wred  = (const float*)d_in[3];
  const float* bred  = (const float*)d_in[4];
  const float* Wspan = (const float*)d_in[5];
  const float* bspan = (const float*)d_in[6];
  const float* W2    = (const float*)d_in[7];
  const float* b2    = (const float*)d_in[8];
  const float* Weca  = (const float*)d_in[9];

  ushort_t* shuf    = (ushort_t*)d_ws;                        // 64 MiB records
  float*    gate    = (float*)((char*)d_ws + 67108864);       // 512 B
  ushort_t* wpack   = (ushort_t*)((char*)d_ws + 67108864 + 1024); // 18.4 KiB
  float*    scratch = (float*)d_out;  // 2048*16 floats; overwritten by k5

  k0_pack<<<9, 128, 0, stream>>>(W2, wpack);
  k12    <<<4096, 256, 0, stream>>>(x, W1, b1, Wred, bred, Wspan, bspan, shuf);
  k3_conv2<<<2048, 256, 0, stream>>>(shuf, wpack, b2, scratch);
  k4_gate<<<8, 256, 0, stream>>>(scratch, Weca, gate);
  k5_scale<<<8192, 256, 0, stream>>>((const f32x4*)x, gate, (f32x4*)d_out);
}